// Round 12
// baseline (71.996 us; speedup 1.0000x reference)
//
#include <hip/hip_runtime.h>
#include <math.h>

// Problem constants
#define B_   128
#define IN_  1024
#define OUT_ 1024
#define E_   32

// moe_main tiling
#define SLAB  64                 // i-rows per block
#define NSLAB (IN_ / SLAB)       // 16
#define S_    16                 // samples per group pass
#define RB    4                  // rows per prefetch batch
#define THR   512

// ws layout (bytes)
#define WS_ROUTE   0
#define WS_PART    65536          // 2*NSLAB*B_*OUT_ floats = 16 MB

// ---------------- Kernel A: routing, one block per (sample, router) --------------
// route layout: route[(b*2 + r)*4] = [idx0, idx1, p0, p1]  (idx bit-cast)
// r==1 blocks additionally write out[b] = pb0*eb[ib0] + pb1*eb[ib1] (bias init).
__global__ __launch_bounds__(256) void route_kernel(
    const float* __restrict__ x, const float* __restrict__ rw,
    const float* __restrict__ brw, const float* __restrict__ eb,
    float* __restrict__ route, float* __restrict__ out) {
  int b = blockIdx.x;
  int r = blockIdx.y;
  int t = threadIdx.x;
  const float* w = r ? brw : rw;

  __shared__ float xs[IN_];
  __shared__ float part[8][E_];
  __shared__ float lg[E_];
  __shared__ float res[4];

  ((float4*)xs)[t] = ((const float4*)(x + (size_t)b * IN_))[t];
  __syncthreads();

  int e  = t & 31;
  int ic = t >> 5;
  int base = ic * 128;
  float acc = 0.f;
  #pragma unroll 8
  for (int i = 0; i < 128; ++i)
    acc += xs[base + i] * w[(size_t)(base + i) * E_ + e];
  part[ic][e] = acc;
  __syncthreads();

  if (t < E_) {
    float s = 0.f;
    #pragma unroll
    for (int q = 0; q < 8; ++q) s += part[q][t];
    lg[t] = s;
  }
  __syncthreads();

  if (t == 0) {
    int bi0 = -1, bi1 = -1;
    float v0 = -INFINITY, v1 = -INFINITY;
    for (int ee = 0; ee < E_; ++ee) {
      float v = lg[ee];
      if (v > v0) { v1 = v0; bi1 = bi0; v0 = v; bi0 = ee; }
      else if (v > v1) { v1 = v; bi1 = ee; }
    }
    float p0 = 1.f / (1.f + expf(v1 - v0));
    float* rp = route + ((size_t)b * 2 + r) * 4;
    rp[0] = __int_as_float(bi0);
    rp[1] = __int_as_float(bi1);
    rp[2] = p0;
    rp[3] = 1.f - p0;
    res[0] = __int_as_float(bi0);
    res[1] = __int_as_float(bi1);
    res[2] = p0;
    res[3] = 1.f - p0;
  }

  if (r == 1) {
    __syncthreads();
    int ib0 = __float_as_int(res[0]);
    int ib1 = __float_as_int(res[1]);
    float pb0 = res[2], pb1 = res[3];
    float4 b0 = ((const float4*)(eb + (size_t)ib0 * OUT_))[t];
    float4 b1 = ((const float4*)(eb + (size_t)ib1 * OUT_))[t];
    float4 o;
    o.x = pb0 * b0.x + pb1 * b1.x;
    o.y = pb0 * b0.y + pb1 * b1.y;
    o.z = pb0 * b0.z + pb1 * b1.z;
    o.w = pb0 * b0.w + pb1 * b1.w;
    ((float4*)(out + (size_t)b * OUT_))[t] = o;
  }
}

// ---------------- Kernel B: expert matvecs, 3-deep reg prefetch, fused lists -----
// block = (e, slab of 64 i-rows); 512 threads, thread t owns output cols
// [2t, 2t+1], directly consuming its own coalesced weight loads (block-level
// linear stream). 3 prefetch buffers (bufA/bufB/bufC: 8 rows in flight/wave).
// Per-expert sample list scanned in-block from route (hidden under the
// issue-early batch-0/1 weight loads). Partials to disjoint ws slots via
// plain stores (zero atomics).
__global__ __launch_bounds__(THR) void moe_main(
    const float* __restrict__ x, const float* __restrict__ ew,
    const float* __restrict__ route, float* __restrict__ part) {
  int e    = blockIdx.x;
  int slab = blockIdx.y;

  __shared__ float  xs[SLAB][S_];   // [i][s], rows 64B-aligned
  __shared__ float4 rsh[B_];
  __shared__ int    bs[S_];
  __shared__ int    ks[S_];
  __shared__ float  ps[S_];
  __shared__ int    ls_b[B_];
  __shared__ int    ls_k[B_];
  __shared__ float  ls_p[B_];
  __shared__ int    cnt_sh;

  int t  = threadIdx.x;
  int i0 = slab * SLAB;
  const float* wslab = ew + ((size_t)e * IN_ + i0) * OUT_;
  const float* wp0 = wslab + 2 * t;

  // issue-early: batches 0 and 1 of the weight stream (independent of routing)
  float2 bufA[RB], bufB[RB];
  #pragma unroll
  for (int r = 0; r < RB; ++r) bufA[r] = *(const float2*)(wp0 + (size_t)r * OUT_);
  #pragma unroll
  for (int r = 0; r < RB; ++r) bufB[r] = *(const float2*)(wp0 + (size_t)(RB + r) * OUT_);

  // route cache + per-expert list scan (overlaps the loads above)
  if (t < B_) rsh[t] = *(const float4*)(route + (size_t)t * 8);
  __syncthreads();
  if (t == 0) {
    int c = 0;
    for (int b = 0; b < B_; ++b) {
      float4 r = rsh[b];
      if (__float_as_int(r.x) == e)      { ls_b[c] = b; ls_k[c] = 0; ls_p[c] = r.z; ++c; }
      else if (__float_as_int(r.y) == e) { ls_b[c] = b; ls_k[c] = 1; ls_p[c] = r.w; ++c; }
    }
    cnt_sh = c;
  }
  __syncthreads();
  int c = cnt_sh;
  if (c == 0) return;

  for (int g0 = 0; g0 < c; g0 += S_) {
    if (g0 > 0) {
      // re-issue batches 0/1 for this pass (weights re-streamed per 16 samples)
      #pragma unroll
      for (int r = 0; r < RB; ++r) bufA[r] = *(const float2*)(wp0 + (size_t)r * OUT_);
      #pragma unroll
      for (int r = 0; r < RB; ++r) bufB[r] = *(const float2*)(wp0 + (size_t)(RB + r) * OUT_);
      __syncthreads();   // previous pass's xs readers done
    }
    if (t < S_) {
      int idx = min(g0 + t, c - 1);
      bs[t] = ls_b[idx];
      ks[t] = ls_k[idx];
      ps[t] = (g0 + t < c) ? ls_p[idx] : 0.f;
    }
    __syncthreads();

    // stage x transposed: thread t -> (s = t&15, row pair 2*(t>>4)), float2
    {
      int s  = t & 15;
      int ip = t >> 4;                    // 0..31
      const float* xr = x + (size_t)bs[s] * IN_ + i0 + 2 * ip;
      float2 v = *(const float2*)xr;
      xs[2 * ip][s]     = v.x;
      xs[2 * ip + 1][s] = v.y;
    }
    __syncthreads();

    float2 acc[S_];
    #pragma unroll
    for (int s = 0; s < S_; ++s) acc[s] = make_float2(0.f, 0.f);

    #pragma unroll 2
    for (int ib = 0; ib < SLAB; ib += RB) {
      // issue batch ib+2RB (3-deep: 8 rows in flight while computing)
      float2 bufC[RB];
      bool has2 = (ib + 2 * RB < SLAB);
      if (has2) {
        const float* wp = wp0 + (size_t)(ib + 2 * RB) * OUT_;
        #pragma unroll
        for (int r = 0; r < RB; ++r) bufC[r] = *(const float2*)(wp + (size_t)r * OUT_);
      }

      // consume bufA: rows ib..ib+RB-1 (all indexing static)
      #pragma unroll
      for (int r = 0; r < RB; ++r) {
        const float4* xr = (const float4*)xs[ib + r];
        float4 xa = xr[0], xb = xr[1], xc = xr[2], xd = xr[3];
        float2 wv = bufA[r];
        acc[0].x  += xa.x * wv.x;  acc[0].y  += xa.x * wv.y;
        acc[1].x  += xa.y * wv.x;  acc[1].y  += xa.y * wv.y;
        acc[2].x  += xa.z * wv.x;  acc[2].y  += xa.z * wv.y;
        acc[3].x  += xa.w * wv.x;  acc[3].y  += xa.w * wv.y;
        acc[4].x  += xb.x * wv.x;  acc[4].y  += xb.x * wv.y;
        acc[5].x  += xb.y * wv.x;  acc[5].y  += xb.y * wv.y;
        acc[6].x  += xb.z * wv.x;  acc[6].y  += xb.z * wv.y;
        acc[7].x  += xb.w * wv.x;  acc[7].y  += xb.w * wv.y;
        acc[8].x  += xc.x * wv.x;  acc[8].y  += xc.x * wv.y;
        acc[9].x  += xc.y * wv.x;  acc[9].y  += xc.y * wv.y;
        acc[10].x += xc.z * wv.x;  acc[10].y += xc.z * wv.y;
        acc[11].x += xc.w * wv.x;  acc[11].y += xc.w * wv.y;
        acc[12].x += xd.x * wv.x;  acc[12].y += xd.x * wv.y;
        acc[13].x += xd.y * wv.x;  acc[13].y += xd.y * wv.y;
        acc[14].x += xd.z * wv.x;  acc[14].y += xd.z * wv.y;
        acc[15].x += xd.w * wv.x;  acc[15].y += xd.w * wv.y;
      }

      // rotate: A <- B <- C
      #pragma unroll
      for (int r = 0; r < RB; ++r) bufA[r] = bufB[r];
      if (has2) {
        #pragma unroll
        for (int r = 0; r < RB; ++r) bufB[r] = bufC[r];
      }
    }

    // epilogue: plain float2 store into the disjoint partial slot
    #pragma unroll
    for (int s = 0; s < S_; ++s) {
      if (g0 + s < c) {
        float p = ps[s];
        float2 v = make_float2(p * acc[s].x, p * acc[s].y);
        *(float2*)(part + (((size_t)ks[s] * NSLAB + slab) * B_ + bs[s]) * OUT_ + 2 * t) = v;
      }
    }
  }
}

// ---------------- Kernel D: reduce partials into out ----------------
// out[b][col] = bias(already in out) + sum_{k,slab} part[k][slab][b][col].
__global__ __launch_bounds__(256) void reduce_kernel(
    const float* __restrict__ part, float* __restrict__ out) {
  int b = blockIdx.x;
  int t = threadIdx.x;                 // 256, col = 4t
  float4 a = ((const float4*)(out + (size_t)b * OUT_))[t];
  #pragma unroll
  for (int k = 0; k < 2; ++k) {
    #pragma unroll
    for (int sl = 0; sl < NSLAB; ++sl) {
      float4 v = ((const float4*)(part + (((size_t)k * NSLAB + sl) * B_ + b) * OUT_))[t];
      a.x += v.x; a.y += v.y; a.z += v.z; a.w += v.w;
    }
  }
  ((float4*)(out + (size_t)b * OUT_))[t] = a;
}

extern "C" void kernel_launch(void* const* d_in, const int* in_sizes, int n_in,
                              void* d_out, int out_size, void* d_ws, size_t ws_size,
                              hipStream_t stream) {
  const float* x   = (const float*)d_in[0];
  const float* rw  = (const float*)d_in[1];
  const float* brw = (const float*)d_in[2];
  const float* ew  = (const float*)d_in[3];
  const float* eb  = (const float*)d_in[4];
  float* out = (float*)d_out;

  char* ws = (char*)d_ws;
  float* route = (float*)(ws + WS_ROUTE);
  float* part  = (float*)(ws + WS_PART);   // 2*NSLAB*B_*OUT_ floats = 16 MB

  route_kernel<<<dim3(B_, 2), 256, 0, stream>>>(x, rw, brw, eb, route, out);
  moe_main<<<dim3(E_, NSLAB), THR, 0, stream>>>(x, ew, route, part);
  reduce_kernel<<<B_, 256, 0, stream>>>(part, out);
}